// Round 22
// baseline (157.964 us; speedup 1.0000x reference)
//
#include <hip/hip_runtime.h>

// ieHGCNConv on MI355X — round 22:
//  - gemm K-loop barriers hand-rolled (T4): raw s_barrier + counted vmcnt(8)
//    so A-prefetch loads SURVIVE the staging barrier (B loads issued first =
//    oldest = drained; pf loads fly across and complete under next phase).
//    __syncthreads()'s implicit vmcnt(0) was force-draining every prefetch
//    within ~250cy of issue (rounds 19-21 all pinned at 92us / 6.6% MfmaUtil).
//  - pf issued unconditionally with wrapped index so vmcnt count is uniform.
//  - otherwise identical to round 21.
// NA=NP=50000, E=800000, IN=256, OUT=128.
#define MP   50048     // 391*128 padded rows
#define NB   391       // coarse buckets (dst>>7)
#define GCAP 3072      // per bucket final capacity
#define CHUNK 4096     // edges per pass-A block
#define GEMM_BLKS 1960 // 8 xcd * 5 slabs * 49 m-groups (5 blocks idle)

typedef short bf16x8 __attribute__((ext_vector_type(8)));
typedef float f32x4 __attribute__((ext_vector_type(4)));

__device__ __forceinline__ unsigned short f2bf(float f) {
  unsigned u = __float_as_uint(f);
  u += 0x7FFF + ((u >> 16) & 1);   // round-to-nearest-even
  return (unsigned short)(u >> 16);
}
__device__ __forceinline__ float b2f(unsigned short u) {
  return __uint_as_float((unsigned)u << 16);
}
__device__ __forceinline__ float fexp(float x) {
  return __builtin_amdgcn_exp2f(x * 1.4426950408889634f);
}
__device__ __forceinline__ float eluf(float x) { return x > 0.f ? x : fexp(x) - 1.0f; }
__device__ __forceinline__ float frcp(float x) { return __builtin_amdgcn_rcpf(x); }

// ---------- prep: build_bt + precompute + passA ----------
__global__ __launch_bounds__(256) void k_prep(
    const float* __restrict__ Wself_a, const float* __restrict__ Wc_writes,
    const float* __restrict__ Wself_p, const float* __restrict__ Wc_wb,
    const float* __restrict__ Wc_cites,
    unsigned short* __restrict__ BaT, unsigned short* __restrict__ BpT,
    const float* Wq_a, const float* bq_a, const float* Wq_p, const float* bq_p,
    const float* Wk_a, const float* bk_a, const float* Wk_p, const float* bk_p,
    const float* Wal_a, const float* bal_a, const float* Wal_p, const float* bal_p,
    const float* War_a, const float* bar_a, const float* War_p, const float* bar_p,
    float* __restrict__ vecs,
    const int* __restrict__ s0, const int* __restrict__ d0,
    const int* __restrict__ s1, const int* __restrict__ d1,
    const int* __restrict__ s2, const int* __restrict__ d2,
    unsigned* __restrict__ coarse, int* __restrict__ offs, int E, int ablocks) {
  __shared__ __align__(16) char lds[19968];
  const int blk = blockIdx.x, t = threadIdx.x;
  if (blk < 640) {
    int idx = blk * 256 + t;
    if (idx < 65536) {                 // BaT [256][256]
      int n = idx >> 8, k = idx & 255;
      float v = (n < 128) ? Wself_a[k * 128 + n] : Wc_writes[k * 128 + (n - 128)];
      BaT[idx] = f2bf(v);
    } else if (idx < 65536 + 98304) {  // BpT [384][256]
      int j = idx - 65536;
      int n = j >> 8, k = j & 255;
      float v;
      if (n < 128)       v = Wself_p[k * 128 + n];
      else if (n < 256)  v = Wc_wb[k * 128 + (n - 128)];
      else               v = Wc_cites[k * 128 + (n - 256)];
      BpT[j] = f2bf(v);
    }
  } else if (blk == 640) {
    if (t >= 128) return;
    int j = t;
    float vra = 0.f, vla = 0.f, vrp = 0.f, vlp = 0.f;
    for (int k = 0; k < 64; k++) {
      vra += Wq_a[j * 64 + k] * War_a[k];
      vla += Wk_a[j * 64 + k] * Wal_a[k];
      vrp += Wq_p[j * 64 + k] * War_p[k];
      vlp += Wk_p[j * 64 + k] * Wal_p[k];
    }
    vecs[j] = vla; vecs[128 + j] = vra; vecs[256 + j] = vlp; vecs[384 + j] = vrp;
    if (j == 0) {
      float cra = bar_a[0], cla = bal_a[0], crp = bar_p[0], clp = bal_p[0];
      for (int k = 0; k < 64; k++) {
        cra += bq_a[k] * War_a[k];
        cla += bk_a[k] * Wal_a[k];
        crp += bq_p[k] * War_p[k];
        clp += bk_p[k] * Wal_p[k];
      }
      vecs[512] = cla; vecs[513] = cra; vecs[514] = clp; vecs[515] = crp;
    }
  } else {
    // ---- passA: in-LDS bucket sort (double-read of edges), streaming write-out ----
    const int pa = blk - 641;
    const int rel = pa / ablocks, reg = pa % ablocks;
    const int* S = rel == 0 ? s0 : (rel == 1 ? s1 : s2);
    const int* D = rel == 0 ? d0 : (rel == 1 ? d1 : d2);
    const int base = reg * CHUNK;
    const int cnt = min(CHUNK, E - base);
    unsigned* sorted = (unsigned*)lds;            // 16384
    int* hist = (int*)(lds + 16384);              // 1792 (448) -> reused as cursor
    int* pre  = (int*)(lds + 18176);              // 1792
    for (int i = t; i < 448; i += 256) hist[i] = 0;
    __syncthreads();
    for (int i = t; i < cnt; i += 256)
      atomicAdd(&hist[D[base + i] >> 7], 1);
    __syncthreads();
    if (t < 64) {
      int carry = 0;
#pragma unroll
      for (int k = 0; k < 7; k++) {
        int v = hist[k * 64 + t];
        int inc = v;
#pragma unroll
        for (int o = 1; o < 64; o <<= 1) { int x = __shfl_up(inc, o); if (t >= o) inc += x; }
        pre[k * 64 + t] = carry + inc - v;
        carry += __shfl(inc, 63);
      }
    }
    __syncthreads();
    for (int b = t; b < 448; b += 256) hist[b] = pre[b];   // hist becomes cursor
    __syncthreads();
    for (int i = t; i < cnt; i += 256) {
      int s = S[base + i], d = D[base + i];
      int pos = atomicAdd(&hist[d >> 7], 1);
      sorted[pos] = ((unsigned)s << 7) | (unsigned)(d & 127);
    }
    __syncthreads();
    unsigned* creg = coarse + (size_t)(rel * ablocks + reg) * CHUNK;
    for (int i = t; i < cnt; i += 256) creg[i] = sorted[i];
    int* oreg = offs + (rel * ablocks + reg) * (NB + 1);
    for (int b = t; b < NB + 1; b += 256) oreg[b] = pre[b];  // pre[NB] == cnt
  }
}

// ---------- fused: 5-slab GEMM (A reg-staged, counted-vmcnt pipeline) + passB ----------
__global__ __launch_bounds__(256) void k_gemmA(
    const float* __restrict__ ha, const float* __restrict__ hp, int NAv, int NPv,
    const unsigned short* __restrict__ BaT, const unsigned short* __restrict__ BpT,
    unsigned short* __restrict__ za, unsigned short* __restrict__ zp,
    unsigned char* __restrict__ mW8, unsigned char* __restrict__ mB8,
    unsigned char* __restrict__ mC8,
    const unsigned* __restrict__ coarse, const int* __restrict__ offs,
    int* __restrict__ g0, int* __restrict__ g1, int* __restrict__ g2,
    int* __restrict__ st0, int* __restrict__ st1, int* __restrict__ st2,
    int* __restrict__ cn0, int* __restrict__ cn1, int* __restrict__ cn2,
    int ablocks) {
  __shared__ __align__(16) char lds[32768];
  const int t = threadIdx.x;
  if ((int)blockIdx.x < GEMM_BLKS) {
    const int xcd = blockIdx.x & 7;
    const int r = blockIdx.x >> 3;
    const int y = r % 5;
    const int m = (r / 5) * 8 + xcd;
    if (m >= 391) return;
    const int m0 = m * 128;
    const float* Afp = (y <= 1) ? ha : hp;
    const int Mvalid = (y <= 1) ? NAv : NPv;
    const unsigned short* Bt =
        (y == 0) ? BaT : (y == 1) ? BaT + 32768 :
        (y == 2) ? BpT : (y == 3) ? BpT + 32768 : BpT + 65536;
    const int lane = t & 63, wave = t >> 6;
    const int wr = wave >> 1, wc = wave & 1;
    const int l15 = lane & 15, l4 = lane >> 4;
    const int srow = t >> 3;
    const int gchunk = (t & 7) ^ (srow & 7);
    char* ldsA = lds;
    char* ldsB = lds + 16384;
    // per-thread A staging geometry (constant across kt)
    const int arow = t >> 1;                 // rows 0..127, 2 threads/row
    const int ach  = (t & 1) * 4;            // chunk group 0 or 4 (4 chunks each)
    const bool avalid = (m0 + arow) < Mvalid;
    const float* abase = Afp + (size_t)(m0 + arow) * 256 + ach * 8;
    f32x4 acc[4][4] = {};
    float4 pf[4][2];
    // prologue: load A for kt=0
#pragma unroll
    for (int c = 0; c < 4; c++) {
      if (avalid) {
        const float* src = abase + c * 8;
        pf[c][0] = *(const float4*)src;
        pf[c][1] = *(const float4*)(src + 4);
      } else {
        pf[c][0] = make_float4(0.f, 0.f, 0.f, 0.f);
        pf[c][1] = pf[c][0];
      }
    }
    for (int kt = 0; kt < 4; kt++) {
      if (kt) {
        // top barrier: protect LDS reuse; do NOT drain pf loads (lgkm only)
        asm volatile("s_waitcnt lgkmcnt(0)" ::: "memory");
        __builtin_amdgcn_s_barrier();
      }
      // B: async bf16 loads FIRST (oldest vmem -> drained by vmcnt(8) below)
      for (int c = 0; c < 4; c++) {
        int row = c * 32 + srow;
        const char* gb = (const char*)Bt + ((size_t)row * 256 + kt * 64 + gchunk * 8) * 2;
        __builtin_amdgcn_global_load_lds(
            (const __attribute__((address_space(1))) void*)gb,
            (__attribute__((address_space(3))) void*)(ldsB + c * 4096 + wave * 1024), 16, 0, 0);
      }
      // write prefetched A (convert fp32->bf16, swizzled slot); compiler inserts
      // the minimal vmcnt wait for pf(kt) (issued last iter, ~1 K-step of cover)
#pragma unroll
      for (int c = 0; c < 4; c++) {
        int ch = ach + c;
        union { unsigned short s[8]; uint4 v; } u;
        u.s[0]=f2bf(pf[c][0].x); u.s[1]=f2bf(pf[c][0].y);
        u.s[2]=f2bf(pf[c][0].z); u.s[3]=f2bf(pf[c][0].w);
        u.s[4]=f2bf(pf[c][1].x); u.s[5]=f2bf(pf[c][1].y);
        u.s[6]=f2bf(pf[c][1].z); u.s[7]=f2bf(pf[c][1].w);
        *(uint4*)(ldsA + arow * 128 + (ch ^ (arow & 7)) * 16) = u.v;
      }
      // issue pf for (kt+1)&3 unconditionally (uniform vmcnt accounting; wrap
      // loads on the last step are L3-hot and unused)
      {
        const int ktn = (kt + 1) & 3;
#pragma unroll
        for (int c = 0; c < 4; c++) {
          if (avalid) {
            const float* src = abase + ktn * 64 + c * 8;
            pf[c][0] = *(const float4*)src;
            pf[c][1] = *(const float4*)(src + 4);
          }
        }
      }
      // staging barrier: drain B's 4 loads (oldest) + all LDS writes; leave the
      // 8 pf loads in flight across the barrier (counted vmcnt — T4)
      asm volatile("s_waitcnt vmcnt(8) lgkmcnt(0)" ::: "memory");
      __builtin_amdgcn_s_barrier();
#pragma unroll
      for (int kk = 0; kk < 2; kk++) {
        bf16x8 a[4], b[4];
#pragma unroll
        for (int i = 0; i < 4; i++) {
          int row = wr * 64 + i * 16 + l15;
          int slot = (kk * 4 + l4) ^ (row & 7);
          a[i] = *(const bf16x8*)(ldsA + row * 128 + slot * 16);
        }
#pragma unroll
        for (int j = 0; j < 4; j++) {
          int row = wc * 64 + j * 16 + l15;
          int slot = (kk * 4 + l4) ^ (row & 7);
          b[j] = *(const bf16x8*)(ldsB + row * 128 + slot * 16);
        }
#pragma unroll
        for (int i = 0; i < 4; i++)
#pragma unroll
          for (int j = 0; j < 4; j++)
            acc[i][j] = __builtin_amdgcn_mfma_f32_16x16x32_bf16(a[i], b[j], acc[i][j], 0, 0, 0);
      }
    }
    if (y == 0 || y == 2) {
      unsigned short* C = (y == 0) ? za : zp;
#pragma unroll
      for (int i = 0; i < 4; i++) {
        int row = m0 + wr * 64 + i * 16 + l4 * 4;
#pragma unroll
        for (int j = 0; j < 4; j++) {
          int col = wc * 64 + j * 16 + l15;
#pragma unroll
          for (int rr = 0; rr < 4; rr++)
            C[(size_t)(row + rr) * 128 + col] = f2bf(acc[i][j][rr]);
        }
      }
    } else {
      unsigned char* C = (y == 1) ? mW8 : (y == 3) ? mB8 : mC8;
#pragma unroll
      for (int i = 0; i < 4; i++) {
        int row = m0 + wr * 64 + i * 16 + l4 * 4;
#pragma unroll
        for (int j = 0; j < 4; j++) {
          int col = wc * 64 + j * 16 + l15;
#pragma unroll
          for (int rr = 0; rr < 4; rr++) {
            int q = __float2int_rn(acc[i][j][rr] * 16.0f) + 128;
            q = max(0, min(255, q));
            C[(size_t)(row + rr) * 128 + col] = (unsigned char)q;
          }
        }
      }
    }
  } else {
    // ---- passB: gather bucket runs from per-region sorted blocks, fine sort ----
    const int bpb = blockIdx.x - GEMM_BLKS;
    const int rel = bpb / NB, b = bpb % NB;
    int* g  = rel == 0 ? g0  : (rel == 1 ? g1  : g2);
    int* st = rel == 0 ? st0 : (rel == 1 ? st1 : st2);
    int* cn = rel == 0 ? cn0 : (rel == 1 ? cn1 : cn2);
    unsigned* eL  = (unsigned*)lds;           // 16384 (cap 4096)
    int* lens     = (int*)(lds + 16384);      // 800 (<=200 regions)
    int* starts   = (int*)(lds + 17184);      // 800
    int* basePos  = (int*)(lds + 17984);      // 804
    int* hist     = (int*)(lds + 18788);      // 512
    int* pre      = (int*)(lds + 19300);      // 512
    int* cur      = (int*)(lds + 19812);      // 512
    for (int r = t; r < ablocks; r += 256) {
      const int* oreg = offs + (rel * ablocks + r) * (NB + 1);
      int s = oreg[b], e = oreg[b + 1];
      starts[r] = s;
      lens[r] = e - s;
    }
    if (t < 128) hist[t] = 0;
    __syncthreads();
    if (t < 64) {
      int carry = 0;
      int nch = (ablocks + 63) >> 6;
      for (int k = 0; k < nch; k++) {
        int idx = k * 64 + t;
        int v = (idx < ablocks) ? lens[idx] : 0;
        int inc = v;
#pragma unroll
        for (int o = 1; o < 64; o <<= 1) { int x = __shfl_up(inc, o); if (t >= o) inc += x; }
        if (idx < ablocks) basePos[idx] = carry + inc - v;
        carry += __shfl(inc, 63);
      }
      if (t == 0) basePos[ablocks] = carry;
    }
    __syncthreads();
    const int n = min(basePos[ablocks], 4096);
    for (int r = t; r < ablocks; r += 256) {
      int s = starts[r], ln = lens[r], bp = basePos[r];
      const unsigned* src = coarse + (size_t)(rel * ablocks + r) * CHUNK + s;
      for (int j = 0; j < ln; j++) {
        int p = bp + j;
        if (p < 4096) eL[p] = src[j];
      }
    }
    __syncthreads();
    for (int i = t; i < n; i += 256) atomicAdd(&hist[eL[i] & 127], 1);
    __syncthreads();
    if (t < 64) {
      int carry = 0;
#pragma unroll
      for (int k = 0; k < 2; k++) {
        int v = hist[k * 64 + t];
        int inc = v;
#pragma unroll
        for (int o = 1; o < 64; o <<= 1) { int x = __shfl_up(inc, o); if (t >= o) inc += x; }
        pre[k * 64 + t] = carry + inc - v;
        carry += __shfl(inc, 63);
      }
    }
    __syncthreads();
    if (t < 128) cur[t] = pre[t];
    __syncthreads();
    for (int i = t; i < n; i += 256) {
      unsigned e = eL[i];
      int pos = atomicAdd(&cur[e & 127], 1);
      if (pos < GCAP) g[b * GCAP + pos] = (int)(e & 0xFFFFFF80u);  // src*128
    }
    if (t < 128) {
      int dst = b * 128 + t;
      int p = min(pre[t], GCAP);
      st[dst] = b * GCAP + p;
      cn[dst] = min(hist[t], GCAP - p);
    }
  }
}

// ---------- SWAR u8 accumulate ----------
__device__ __forceinline__ void accS(uint2 u, unsigned* __restrict__ a) {
  a[0] += u.x & 0x00FF00FFu;
  a[1] += __builtin_amdgcn_perm(0u, u.x, 0x04030401u);   // {0,b3,0,b1}
  a[2] += u.y & 0x00FF00FFu;
  a[3] += __builtin_amdgcn_perm(0u, u.y, 0x04030401u);
}

// single-relation group gather (authors): unroll 8; g holds src*128 byte offsets
__device__ __forceinline__ void gaccG(const unsigned char* __restrict__ base,
                                      const int* __restrict__ g, int s0, int n,
                                      int q, unsigned* __restrict__ a) {
  int i = s0;
  const int end = s0 + n;
  for (; i + 7 < end; i += 8) {
    uint2 u0 = *(const uint2*)(base + (unsigned)g[i]     + q * 8);
    uint2 u1 = *(const uint2*)(base + (unsigned)g[i + 1] + q * 8);
    uint2 u2 = *(const uint2*)(base + (unsigned)g[i + 2] + q * 8);
    uint2 u3 = *(const uint2*)(base + (unsigned)g[i + 3] + q * 8);
    uint2 u4 = *(const uint2*)(base + (unsigned)g[i + 4] + q * 8);
    uint2 u5 = *(const uint2*)(base + (unsigned)g[i + 5] + q * 8);
    uint2 u6 = *(const uint2*)(base + (unsigned)g[i + 6] + q * 8);
    uint2 u7 = *(const uint2*)(base + (unsigned)g[i + 7] + q * 8);
    accS(u0, a); accS(u1, a); accS(u2, a); accS(u3, a);
    accS(u4, a); accS(u5, a); accS(u6, a); accS(u7, a);
  }
  for (; i + 3 < end; i += 4) {
    uint2 u0 = *(const uint2*)(base + (unsigned)g[i]     + q * 8);
    uint2 u1 = *(const uint2*)(base + (unsigned)g[i + 1] + q * 8);
    uint2 u2 = *(const uint2*)(base + (unsigned)g[i + 2] + q * 8);
    uint2 u3 = *(const uint2*)(base + (unsigned)g[i + 3] + q * 8);
    accS(u0, a); accS(u1, a); accS(u2, a); accS(u3, a);
  }
  for (; i < end; i++)
    accS(*(const uint2*)(base + (unsigned)g[i] + q * 8), a);
}

// dual-relation co-issued group gather (papers)
__device__ __forceinline__ void gacc2G(const unsigned char* __restrict__ bA,
                                       const int* __restrict__ gA, int sA, int nA,
                                       const unsigned char* __restrict__ bB,
                                       const int* __restrict__ gB, int sB, int nB,
                                       int q,
                                       unsigned* __restrict__ a, unsigned* __restrict__ b) {
  int iA = sA; const int eA = sA + nA;
  int iB = sB; const int eB = sB + nB;
  bool hA = iA + 3 < eA, hB = iB + 3 < eB;
  while (hA || hB) {
    uint2 wa0, wa1, wa2, wa3, wb0, wb1, wb2, wb3;
    if (hA) {
      wa0 = *(const uint2*)(bA + (unsigned)gA[iA]     + q * 8);
      wa1 = *(const uint2*)(bA + (unsigned)gA[iA + 1] + q * 8);
      wa2 = *(const uint2*)(bA + (unsigned)gA[iA + 2] + q * 8);
      wa3 = *(const uint2*)(bA + (unsigned)gA[iA + 3] + q * 8);
    }
    if (hB) {
      wb0 = *(const uint2*)(bB + (unsigned)gB[iB]     + q * 8);
      wb1 = *(const uint2*)(bB + (unsigned)gB[iB + 1] + q * 8);
      wb2 = *(const uint2*)(bB + (unsigned)gB[iB + 2] + q * 8);
      wb3 = *(const uint2*)(bB + (unsigned)gB[iB + 3] + q * 8);
    }
    if (hA) { accS(wa0, a); accS(wa1, a); accS(wa2, a); accS(wa3, a); iA += 4; }
    if (hB) { accS(wb0, b); accS(wb1, b); accS(wb2, b); accS(wb3, b); iB += 4; }
    hA = iA + 3 < eA; hB = iB + 3 < eB;
  }
  for (; iA < eA; iA++)
    accS(*(const uint2*)(bA + (unsigned)gA[iA] + q * 8), a);
  for (; iB < eB; iB++)
    accS(*(const uint2*)(bB + (unsigned)gB[iB] + q * 8), b);
}

// unpack 4 packed accs (8 cols), bias-correct + average
__device__ __forceinline__ void unpackS(const unsigned* __restrict__ a, float nf,
                                        float invn, const float* __restrict__ bias,
                                        int q, float* __restrict__ c) {
  float s = 0.0625f * invn;
  float off = 128.0f * nf;
  float4 b0 = *(const float4*)(bias + 8 * q);
  float4 b1 = *(const float4*)(bias + 8 * q + 4);
  c[0] = ((float)(a[0] & 0xFFFFu) - off) * s + b0.x;
  c[1] = ((float)(a[1] & 0xFFFFu) - off) * s + b0.y;
  c[2] = ((float)(a[0] >> 16)     - off) * s + b0.z;
  c[3] = ((float)(a[1] >> 16)     - off) * s + b0.w;
  c[4] = ((float)(a[2] & 0xFFFFu) - off) * s + b1.x;
  c[5] = ((float)(a[3] & 0xFFFFu) - off) * s + b1.y;
  c[6] = ((float)(a[2] >> 16)     - off) * s + b1.z;
  c[7] = ((float)(a[3] >> 16)     - off) * s + b1.w;
}

// ---------- fused finalize: 4 nodes per wave (16-lane groups), 16 nodes/block ----------
__global__ __launch_bounds__(256) void k_finalize(
    const unsigned short* __restrict__ za, const unsigned short* __restrict__ zp,
    const unsigned char* __restrict__ mW8, const unsigned char* __restrict__ mB8,
    const unsigned char* __restrict__ mC8,
    const int* __restrict__ gW, const int* __restrict__ stW, const int* __restrict__ cnW,
    const int* __restrict__ gB, const int* __restrict__ stB, const int* __restrict__ cnB,
    const int* __restrict__ gC, const int* __restrict__ stC, const int* __restrict__ cnC,
    const float* __restrict__ bself_a, const float* __restrict__ bc_wb,
    const float* __restrict__ bself_p, const float* __restrict__ bc_writes,
    const float* __restrict__ bc_cites,
    const float* __restrict__ vecs, float* __restrict__ out_a, float* __restrict__ out_p,
    int NAv, int NPv, int pB) {
  const int t = threadIdx.x;
  const int lane = t & 63, q = lane & 15, grp = lane >> 4;
  const bool paper = (int)blockIdx.x < pB;
  const int node = (paper ? blockIdx.x : blockIdx.x - pB) * 16 + (t >> 6) * 4 + grp;

  if (paper) {
    if (node >= NPv) return;
    int nW = cnW[node], sW = stW[node];
    int nC = cnC[node], sC = stC[node];
    uint4 zu = *(const uint4*)((const char*)zp + (size_t)node * 256 + q * 16);
    unsigned aw[4] = {0,0,0,0}, ac[4] = {0,0,0,0};
    gacc2G(mW8, gW, sW, nW, mC8, gC, sC, nC, q, aw, ac);
    float z[8];
    z[0] = b2f((unsigned short)zu.x); z[1] = b2f((unsigned short)(zu.x >> 16));
    z[2] = b2f((unsigned short)zu.y); z[3] = b2f((unsigned short)(zu.y >> 16));
    z[4] = b2f((unsigned short)zu.z); z[5] = b2f((unsigned short)(zu.z >> 16));
    z[6] = b2f((unsigned short)zu.w); z[7] = b2f((unsigned short)(zu.w >> 16));
    float4 bs0 = *(const float4*)(bself_p + 8 * q);
    float4 bs1 = *(const float4*)(bself_p + 8 * q + 4);
    z[0] += bs0.x; z[1] += bs0.y; z[2] += bs0.z; z[3] += bs0.w;
    z[4] += bs1.x; z[5] += bs1.y; z[6] += bs1.z; z[7] += bs1.w;
    float cw[8], cc[8];
    unpackS(aw, (float)nW, frcp(fmaxf((float)nW, 1.0f)), bc_writes, q, cw);
    unpackS(ac, (float)nC, frcp(fmaxf((float)nC, 1.0f)), bc_cites, q, cc);
    float vl[8], vr[8];
    *(float4*)&vl[0] = *(const float4*)(vecs + 256 + 8 * q);
    *(float4*)&vl[4] = *(const float4*)(vecs + 256 + 8 * q + 4);
    *(float4*)&vr[0] = *(const float4*)(vecs + 384 + 8 * q);
    *(float4*)&vr[4] = *(const float4*)(vecs + 384 + 8 * q + 4);
    float srz = 0.f, slz = 0.f, slw = 0.f, slc = 0.f;
#pragma unroll
    for (int j = 0; j < 8; j++) {
      srz += z[j] * vr[j]; slz += z[j] * vl[j];
      slw += cw[j] * vl[j]; slc += cc[j] * vl[j];
    }
#pragma unroll
    for (int off = 8; off; off >>= 1) {
      srz += __shfl_xor(srz, off); slz += __shfl_xor(slz, off);
      slw += __shfl_xor(slw, off); slc += __shfl_xor(slc, off);
    }
    float cl = vecs[514], cr = vecs[515];
    float h_r = srz + cr;
    float att_s = eluf(slz + cl + h_r);
    float e_w  = eluf(slw + cl + h_r);
    float e_c  = eluf(slc + cl + h_r);
    float mx = fmaxf(att_s, fmaxf(e_w, e_c));
    float w0 = fexp(att_s - mx), w1 = fexp(e_w - mx), w2 = fexp(e_c - mx);
    float winv = frcp(w0 + w1 + w2);
    w0 *= winv; w1 *= winv; w2 *= winv;
    float o[8];
#pragma unroll
    for (int j = 0; j < 8; j++) o[j] = eluf(w0 * z[j] + w1 * cw[j] + w2 * cc[j]);
    *(float4*)(out_p + (size_t)node * 128 + 8 * q)     = *(float4*)&o[0];
    *(float4*)(out_p + (size_t)node * 128 + 8 * q + 4) = *(float4*)&o[4];
  } else {
    if (node >= NAv) return;
    int nB_ = cnB[node], sB = stB[node];
    uint4 zu = *(const uint4*)((const char*)za + (size_t)node * 256 + q * 16);
    unsigned ab[4] = {0,0,0,0};
    gaccG(mB8, gB, sB, nB_, q, ab);
    float z[8];
    z[0] = b2f((unsigned short)zu.x); z[1] = b2f((unsigned short)(zu.x >> 16));
    z[2] = b2f((unsigned short)zu.y); z[3] = b2f((unsigned short)(zu.y >> 16));
    z[4] = b2f((unsigned short)zu.z); z[5] = b2f((unsigned short)(zu.z >> 16));
    z[6] = b2f((unsigned short)zu.w); z[7] = b2f((unsigned short)(zu.w >> 16));
    float4 bs0 = *(const float4*)(bself_a + 8 * q);
    float4 bs1 = *(const float4*)(bself_a + 8 * q + 4);
    z[0] += bs0.x; z[1] += bs0.y; z[2] += bs0.z; z[3] += bs0.w;
    z[4] += bs1.x; z[5] += bs1.y; z[6] += bs1.z; z[7] += bs1.w;
    float cb[8];
    unpackS(ab, (float)nB_, frcp(fmaxf((float)nB_, 1.0f)), bc_wb, q, cb);
    float vl[8], vr[8];
    *(float4*)&vl[0] = *(const float4*)(vecs + 8 * q);
    *(float4*)&vl[4] = *(const float4*)(vecs + 8 * q + 4);
    *(float4*)&vr[0] = *(const float4*)(vecs + 128 + 8 * q);
    *(float4*)&vr[4] = *(const float4*)(vecs + 128 + 8 * q + 4);
    float srz = 0.f, slz = 0.f, slb = 0.f;
#pragma unroll
    for (int j = 0; j < 8; j++) {
      srz += z[j] * vr[j]; slz += z[j] * vl[j];
      slb += cb[j] * vl[j];
    }
#pragma unroll
    for (int off = 8; off; off >>= 1) {
      srz += __shfl_xor(srz, off); slz += __shfl_xor(slz, off);
      slb += __shfl_xor(slb, off);
    }
    float cl = vecs[512], cr = vecs[513];
    float h_r = srz + cr;
    float att_s = eluf(slz + cl + h_r);
    float e_b  = eluf(slb + cl + h_r);
    float mx = fmaxf(att_s, e_b);
    float w0 = fexp(att_s - mx), w1 = fexp(e_b - mx);
    float winv = frcp(w0 + w1);
    w0 *= winv; w1 *= winv;
    float o[8];
#pragma unroll
    for (int j = 0; j < 8; j++) o[j] = eluf(w0 * z[j] + w1 * cb[j]);
    *(float4*)(out_a + (size_t)node * 128 + 8 * q)     = *(float4*)&o[0];
    *(float4*)(out_a + (size_t)node * 128 + 8 * q + 4) = *(float4*)&o[4];
  }
}

extern "C" void kernel_launch(void* const* d_in, const int* in_sizes, int n_in,
                              void* d_out, int out_size, void* d_ws, size_t ws_size,
                              hipStream_t stream) {
  const float* h_a      = (const float*)d_in[0];
  const float* h_p      = (const float*)d_in[1];
  const float* Wself_a  = (const float*)d_in[2];  const float* bself_a = (const float*)d_in[3];
  const float* Wself_p  = (const float*)d_in[4];  const float* bself_p = (const float*)d_in[5];
  const float* Wq_a = (const float*)d_in[6];  const float* bq_a = (const float*)d_in[7];
  const float* Wq_p = (const float*)d_in[8];  const float* bq_p = (const float*)d_in[9];
  const float* Wk_a = (const float*)d_in[10]; const float* bk_a = (const float*)d_in[11];
  const float* Wk_p = (const float*)d_in[12]; const float* bk_p = (const float*)d_in[13];
  const float* Wal_a = (const float*)d_in[14]; const float* bal_a = (const float*)d_in[15];
  const float* Wal_p = (const float*)d_in[16]; const float* bal_p = (const float*)d_in[17];
  const float* War_a = (const float*)d_in[18]; const float* bar_a = (const float*)d_in[19];
  const float* War_p = (const float*)d_in[20]; const float* bar_p = (const float*)d_in[21];
  const float* Wc_writes = (const float*)d_in[22]; const float* bc_writes = (const float*)d_in[23];
  const float* Wc_wb     = (const float*)d_in[24]; const float* bc_wb     = (const float*)d_in[25];
  const float* Wc_cites  = (const float*)d_in[26]; const float* bc_cites  = (const float*)d_in[27];
  const int* w_src = (const int*)d_in[28]; const int* w_dst = (const int*)d_in[29];
  const int* b_src = (const int*)d_in[30]; const int* b_dst = (const int*)d_in[31];
  const int* c_src = (const int*)d_in[32]; const int* c_dst = (const int*)d_in[33];

  const int NA = in_sizes[0] / 256;
  const int NP = in_sizes[1] / 256;
  const int E  = in_sizes[28];
  const int ablocks = (E + CHUNK - 1) / CHUNK;   // 196

  char* ws = (char*)d_ws;
  unsigned short* BaT = (unsigned short*)(ws + 0);           // 131,072
  unsigned short* BpT = (unsigned short*)(ws + 131072);      // 196,608
  unsigned short* za  = (unsigned short*)(ws + 327680);      // MP*128*2 = 12,812,288
  unsigned short* zp  = (unsigned short*)(ws + 13139968);    // 12,812,288
  unsigned char* mW8  = (unsigned char*)(ws + 25952256);     // MP*128 = 6,406,144
  unsigned char* mB8  = (unsigned char*)(ws + 32358400);     // 6,406,144
  unsigned char* mC8  = (unsigned char*)(ws + 38764544);     // 6,406,144
  float* vecs = (float*)(ws + 45170688);                     // 2,064

  unsigned* coarse = (unsigned*)(ws + 45176832);             // 3*196*4096*4 = 9,633,792
  int*      offs   = (int*)(ws + 54810624);                  // 3*196*392*4 = 921,984
  int* gW  = (int*)(ws + 55732608);                          // NB*GCAP*4 = 4,804,608
  int* gB  = (int*)(ws + 60537216);
  int* gC  = (int*)(ws + 65341824);
  int* stW = (int*)(ws + 70146432);                          // 200,192 each
  int* stB = (int*)(ws + 70346624);
  int* stC = (int*)(ws + 70546816);
  int* cnW = (int*)(ws + 70747008);
  int* cnB = (int*)(ws + 70947200);
  int* cnC = (int*)(ws + 71147392);

  float* out_a = (float*)d_out;
  float* out_p = out_a + (size_t)NA * 128;

  k_prep<<<641 + 3 * ablocks, 256, 0, stream>>>(
      Wself_a, Wc_writes, Wself_p, Wc_wb, Wc_cites, BaT, BpT,
      Wq_a, bq_a, Wq_p, bq_p, Wk_a, bk_a, Wk_p, bk_p,
      Wal_a, bal_a, Wal_p, bal_p, War_a, bar_a, War_p, bar_p, vecs,
      w_src, w_dst, b_src, b_dst, c_src, c_dst, coarse, offs, E, ablocks);

  k_gemmA<<<GEMM_BLKS + 3 * NB, 256, 0, stream>>>(
      h_a, h_p, NA, NP, BaT, BpT, za, zp, mW8, mB8, mC8,
      coarse, offs, gW, gB, gC, stW, stB, stC, cnW, cnB, cnC, ablocks);

  int pBlk = (NP + 15) / 16, aBlk = (NA + 15) / 16;
  k_finalize<<<pBlk + aBlk, 256, 0, stream>>>(za, zp, mW8, mB8, mC8,
                                              gW, stW, cnW, gB, stB, cnB, gC, stC, cnC,
                                              bself_a, bc_wb, bself_p, bc_writes, bc_cites,
                                              vecs, out_a, out_p, NA, NP, pBlk);
}

// Round 23
// 139.004 us; speedup vs baseline: 1.1364x; 1.1364x over previous
//
#include <hip/hip_runtime.h>

// ieHGCNConv on MI355X — round 23:
//  - A staged as FP32 via global_load_lds (deep DMA queue restores MLP; rounds
//    19-22's reg-staging capped in-flight bytes at 8 float4/wave -> 1.4TB/s).
//    fp32->bf16 conversion moved to fragment-read time (ds_read + f2bf + pack).
//  - BK=32: A fp32 16KB (8-chunk rows, slot=chunk^(row&7)) + B bf16 8KB
//    (4-chunk rows, slot=chunk^((row>>1)&3)); 24KB LDS -> 6 blocks/CU.
//  - tail rows clamp the SOURCE row (padded outputs never read).
//  - otherwise identical to round 19 (no convert pass, streaming passA, passB
//    in gemm tail, 4-nodes/wave finalize).
// NA=NP=50000, E=800000, IN=256, OUT=128.
#define MP   50048     // 391*128 padded rows
#define NB   391       // coarse buckets (dst>>7)
#define GCAP 3072      // per bucket final capacity
#define CHUNK 4096     // edges per pass-A block
#define GEMM_BLKS 1960 // 8 xcd * 5 slabs * 49 m-groups (5 blocks idle)

typedef short bf16x8 __attribute__((ext_vector_type(8)));
typedef float f32x4 __attribute__((ext_vector_type(4)));

__device__ __forceinline__ unsigned short f2bf(float f) {
  unsigned u = __float_as_uint(f);
  u += 0x7FFF + ((u >> 16) & 1);   // round-to-nearest-even
  return (unsigned short)(u >> 16);
}
__device__ __forceinline__ float b2f(unsigned short u) {
  return __uint_as_float((unsigned)u << 16);
}
__device__ __forceinline__ float fexp(float x) {
  return __builtin_amdgcn_exp2f(x * 1.4426950408889634f);
}
__device__ __forceinline__ float eluf(float x) { return x > 0.f ? x : fexp(x) - 1.0f; }
__device__ __forceinline__ float frcp(float x) { return __builtin_amdgcn_rcpf(x); }

// ---------- prep: build_bt + precompute + passA ----------
__global__ __launch_bounds__(256) void k_prep(
    const float* __restrict__ Wself_a, const float* __restrict__ Wc_writes,
    const float* __restrict__ Wself_p, const float* __restrict__ Wc_wb,
    const float* __restrict__ Wc_cites,
    unsigned short* __restrict__ BaT, unsigned short* __restrict__ BpT,
    const float* Wq_a, const float* bq_a, const float* Wq_p, const float* bq_p,
    const float* Wk_a, const float* bk_a, const float* Wk_p, const float* bk_p,
    const float* Wal_a, const float* bal_a, const float* Wal_p, const float* bal_p,
    const float* War_a, const float* bar_a, const float* War_p, const float* bar_p,
    float* __restrict__ vecs,
    const int* __restrict__ s0, const int* __restrict__ d0,
    const int* __restrict__ s1, const int* __restrict__ d1,
    const int* __restrict__ s2, const int* __restrict__ d2,
    unsigned* __restrict__ coarse, int* __restrict__ offs, int E, int ablocks) {
  __shared__ __align__(16) char lds[19968];
  const int blk = blockIdx.x, t = threadIdx.x;
  if (blk < 640) {
    int idx = blk * 256 + t;
    if (idx < 65536) {                 // BaT [256][256]
      int n = idx >> 8, k = idx & 255;
      float v = (n < 128) ? Wself_a[k * 128 + n] : Wc_writes[k * 128 + (n - 128)];
      BaT[idx] = f2bf(v);
    } else if (idx < 65536 + 98304) {  // BpT [384][256]
      int j = idx - 65536;
      int n = j >> 8, k = j & 255;
      float v;
      if (n < 128)       v = Wself_p[k * 128 + n];
      else if (n < 256)  v = Wc_wb[k * 128 + (n - 128)];
      else               v = Wc_cites[k * 128 + (n - 256)];
      BpT[j] = f2bf(v);
    }
  } else if (blk == 640) {
    if (t >= 128) return;
    int j = t;
    float vra = 0.f, vla = 0.f, vrp = 0.f, vlp = 0.f;
    for (int k = 0; k < 64; k++) {
      vra += Wq_a[j * 64 + k] * War_a[k];
      vla += Wk_a[j * 64 + k] * Wal_a[k];
      vrp += Wq_p[j * 64 + k] * War_p[k];
      vlp += Wk_p[j * 64 + k] * Wal_p[k];
    }
    vecs[j] = vla; vecs[128 + j] = vra; vecs[256 + j] = vlp; vecs[384 + j] = vrp;
    if (j == 0) {
      float cra = bar_a[0], cla = bal_a[0], crp = bar_p[0], clp = bal_p[0];
      for (int k = 0; k < 64; k++) {
        cra += bq_a[k] * War_a[k];
        cla += bk_a[k] * Wal_a[k];
        crp += bq_p[k] * War_p[k];
        clp += bk_p[k] * Wal_p[k];
      }
      vecs[512] = cla; vecs[513] = cra; vecs[514] = clp; vecs[515] = crp;
    }
  } else {
    // ---- passA: in-LDS bucket sort (double-read of edges), streaming write-out ----
    const int pa = blk - 641;
    const int rel = pa / ablocks, reg = pa % ablocks;
    const int* S = rel == 0 ? s0 : (rel == 1 ? s1 : s2);
    const int* D = rel == 0 ? d0 : (rel == 1 ? d1 : d2);
    const int base = reg * CHUNK;
    const int cnt = min(CHUNK, E - base);
    unsigned* sorted = (unsigned*)lds;            // 16384
    int* hist = (int*)(lds + 16384);              // 1792 (448) -> reused as cursor
    int* pre  = (int*)(lds + 18176);              // 1792
    for (int i = t; i < 448; i += 256) hist[i] = 0;
    __syncthreads();
    for (int i = t; i < cnt; i += 256)
      atomicAdd(&hist[D[base + i] >> 7], 1);
    __syncthreads();
    if (t < 64) {
      int carry = 0;
#pragma unroll
      for (int k = 0; k < 7; k++) {
        int v = hist[k * 64 + t];
        int inc = v;
#pragma unroll
        for (int o = 1; o < 64; o <<= 1) { int x = __shfl_up(inc, o); if (t >= o) inc += x; }
        pre[k * 64 + t] = carry + inc - v;
        carry += __shfl(inc, 63);
      }
    }
    __syncthreads();
    for (int b = t; b < 448; b += 256) hist[b] = pre[b];   // hist becomes cursor
    __syncthreads();
    for (int i = t; i < cnt; i += 256) {
      int s = S[base + i], d = D[base + i];
      int pos = atomicAdd(&hist[d >> 7], 1);
      sorted[pos] = ((unsigned)s << 7) | (unsigned)(d & 127);
    }
    __syncthreads();
    unsigned* creg = coarse + (size_t)(rel * ablocks + reg) * CHUNK;
    for (int i = t; i < cnt; i += 256) creg[i] = sorted[i];
    int* oreg = offs + (rel * ablocks + reg) * (NB + 1);
    for (int b = t; b < NB + 1; b += 256) oreg[b] = pre[b];  // pre[NB] == cnt
  }
}

// ---------- fused: 5-slab GEMM (fp32 A via global_load_lds, BK=32) + passB ----------
__global__ __launch_bounds__(256) void k_gemmA(
    const float* __restrict__ ha, const float* __restrict__ hp, int NAv, int NPv,
    const unsigned short* __restrict__ BaT, const unsigned short* __restrict__ BpT,
    unsigned short* __restrict__ za, unsigned short* __restrict__ zp,
    unsigned char* __restrict__ mW8, unsigned char* __restrict__ mB8,
    unsigned char* __restrict__ mC8,
    const unsigned* __restrict__ coarse, const int* __restrict__ offs,
    int* __restrict__ g0, int* __restrict__ g1, int* __restrict__ g2,
    int* __restrict__ st0, int* __restrict__ st1, int* __restrict__ st2,
    int* __restrict__ cn0, int* __restrict__ cn1, int* __restrict__ cn2,
    int ablocks) {
  __shared__ __align__(16) char lds[24576];
  const int t = threadIdx.x;
  if ((int)blockIdx.x < GEMM_BLKS) {
    const int xcd = blockIdx.x & 7;
    const int r = blockIdx.x >> 3;
    const int y = r % 5;
    const int m = (r / 5) * 8 + xcd;
    if (m >= 391) return;
    const int m0 = m * 128;
    const float* Afp = (y <= 1) ? ha : hp;
    const int Mvalid = (y <= 1) ? NAv : NPv;
    const unsigned short* Bt =
        (y == 0) ? BaT : (y == 1) ? BaT + 32768 :
        (y == 2) ? BpT : (y == 3) ? BpT + 32768 : BpT + 65536;
    const int lane = t & 63, wave = t >> 6;
    const int wr = wave >> 1, wc = wave & 1;
    const int l15 = lane & 15, l4 = lane >> 4;
    // A staging: per round c, thread t covers (row = c*32 + t>>3, pos = t&7);
    // LDS slot pos holds global chunk pos ^ (row&7); source pre-swizzled.
    const int srowA = t >> 3;
    const int gchA  = (t & 7) ^ (srowA & 7);
    // B staging: per round c, (row = c*64 + t>>2, pos = t&3); swz = (row>>1)&3.
    const int srowB = t >> 2;
    const int gchB  = (t & 3) ^ ((t >> 3) & 3);
    char* ldsA = lds;            // 16384: fp32 A tile [128 rows][8 chunks of 16B]
    char* ldsB = lds + 16384;    //  8192: bf16 B tile [128 rows][4 chunks of 16B]
    f32x4 acc[4][4] = {};
    for (int kt = 0; kt < 8; kt++) {
      if (kt) __syncthreads();
      // A: fp32 DMA (4 rounds x 1KB/wave); tail rows clamp source (outputs unread)
      for (int c = 0; c < 4; c++) {
        int grow = m0 + c * 32 + srowA;
        if (grow >= Mvalid) grow = Mvalid - 1;
        const char* ga = (const char*)Afp + ((size_t)grow * 256 + kt * 32) * 4 + gchA * 16;
        __builtin_amdgcn_global_load_lds(
            (const __attribute__((address_space(1))) void*)ga,
            (__attribute__((address_space(3))) void*)(ldsA + c * 4096 + wave * 1024), 16, 0, 0);
      }
      // B: bf16 DMA (2 rounds)
      for (int c = 0; c < 2; c++) {
        int row = c * 64 + srowB;
        const char* gb = (const char*)Bt + ((size_t)row * 256 + kt * 32) * 2 + gchB * 16;
        __builtin_amdgcn_global_load_lds(
            (const __attribute__((address_space(1))) void*)gb,
            (__attribute__((address_space(3))) void*)(ldsB + c * 4096 + wave * 1024), 16, 0, 0);
      }
      __syncthreads();
      bf16x8 a[4], b[4];
#pragma unroll
      for (int i = 0; i < 4; i++) {
        int row = wr * 64 + i * 16 + l15;
        int sw = row & 7;
        const char* base = ldsA + row * 128;
        f32x4 f0 = *(const f32x4*)(base + (((l4 << 1)    ) ^ sw) * 16);
        f32x4 f1 = *(const f32x4*)(base + (((l4 << 1) | 1) ^ sw) * 16);
        union { unsigned short s[8]; bf16x8 v; } ua;
        ua.s[0] = f2bf(f0[0]); ua.s[1] = f2bf(f0[1]);
        ua.s[2] = f2bf(f0[2]); ua.s[3] = f2bf(f0[3]);
        ua.s[4] = f2bf(f1[0]); ua.s[5] = f2bf(f1[1]);
        ua.s[6] = f2bf(f1[2]); ua.s[7] = f2bf(f1[3]);
        a[i] = ua.v;
      }
#pragma unroll
      for (int j = 0; j < 4; j++) {
        int row = wc * 64 + j * 16 + l15;
        int slot = l4 ^ ((row >> 1) & 3);
        b[j] = *(const bf16x8*)(ldsB + row * 64 + slot * 16);
      }
#pragma unroll
      for (int i = 0; i < 4; i++)
#pragma unroll
        for (int j = 0; j < 4; j++)
          acc[i][j] = __builtin_amdgcn_mfma_f32_16x16x32_bf16(a[i], b[j], acc[i][j], 0, 0, 0);
    }
    if (y == 0 || y == 2) {
      unsigned short* C = (y == 0) ? za : zp;
#pragma unroll
      for (int i = 0; i < 4; i++) {
        int row = m0 + wr * 64 + i * 16 + l4 * 4;
#pragma unroll
        for (int j = 0; j < 4; j++) {
          int col = wc * 64 + j * 16 + l15;
#pragma unroll
          for (int rr = 0; rr < 4; rr++)
            C[(size_t)(row + rr) * 128 + col] = f2bf(acc[i][j][rr]);
        }
      }
    } else {
      unsigned char* C = (y == 1) ? mW8 : (y == 3) ? mB8 : mC8;
#pragma unroll
      for (int i = 0; i < 4; i++) {
        int row = m0 + wr * 64 + i * 16 + l4 * 4;
#pragma unroll
        for (int j = 0; j < 4; j++) {
          int col = wc * 64 + j * 16 + l15;
#pragma unroll
          for (int rr = 0; rr < 4; rr++) {
            int q = __float2int_rn(acc[i][j][rr] * 16.0f) + 128;
            q = max(0, min(255, q));
            C[(size_t)(row + rr) * 128 + col] = (unsigned char)q;
          }
        }
      }
    }
  } else {
    // ---- passB: gather bucket runs from per-region sorted blocks, fine sort ----
    const int bpb = blockIdx.x - GEMM_BLKS;
    const int rel = bpb / NB, b = bpb % NB;
    int* g  = rel == 0 ? g0  : (rel == 1 ? g1  : g2);
    int* st = rel == 0 ? st0 : (rel == 1 ? st1 : st2);
    int* cn = rel == 0 ? cn0 : (rel == 1 ? cn1 : cn2);
    unsigned* eL  = (unsigned*)lds;           // 16384 (cap 4096)
    int* lens     = (int*)(lds + 16384);      // 800 (<=200 regions)
    int* starts   = (int*)(lds + 17184);      // 800
    int* basePos  = (int*)(lds + 17984);      // 804
    int* hist     = (int*)(lds + 18788);      // 512
    int* pre      = (int*)(lds + 19300);      // 512
    int* cur      = (int*)(lds + 19812);      // 512
    for (int r = t; r < ablocks; r += 256) {
      const int* oreg = offs + (rel * ablocks + r) * (NB + 1);
      int s = oreg[b], e = oreg[b + 1];
      starts[r] = s;
      lens[r] = e - s;
    }
    if (t < 128) hist[t] = 0;
    __syncthreads();
    if (t < 64) {
      int carry = 0;
      int nch = (ablocks + 63) >> 6;
      for (int k = 0; k < nch; k++) {
        int idx = k * 64 + t;
        int v = (idx < ablocks) ? lens[idx] : 0;
        int inc = v;
#pragma unroll
        for (int o = 1; o < 64; o <<= 1) { int x = __shfl_up(inc, o); if (t >= o) inc += x; }
        if (idx < ablocks) basePos[idx] = carry + inc - v;
        carry += __shfl(inc, 63);
      }
      if (t == 0) basePos[ablocks] = carry;
    }
    __syncthreads();
    const int n = min(basePos[ablocks], 4096);
    for (int r = t; r < ablocks; r += 256) {
      int s = starts[r], ln = lens[r], bp = basePos[r];
      const unsigned* src = coarse + (size_t)(rel * ablocks + r) * CHUNK + s;
      for (int j = 0; j < ln; j++) {
        int p = bp + j;
        if (p < 4096) eL[p] = src[j];
      }
    }
    __syncthreads();
    for (int i = t; i < n; i += 256) atomicAdd(&hist[eL[i] & 127], 1);
    __syncthreads();
    if (t < 64) {
      int carry = 0;
#pragma unroll
      for (int k = 0; k < 2; k++) {
        int v = hist[k * 64 + t];
        int inc = v;
#pragma unroll
        for (int o = 1; o < 64; o <<= 1) { int x = __shfl_up(inc, o); if (t >= o) inc += x; }
        pre[k * 64 + t] = carry + inc - v;
        carry += __shfl(inc, 63);
      }
    }
    __syncthreads();
    if (t < 128) cur[t] = pre[t];
    __syncthreads();
    for (int i = t; i < n; i += 256) {
      unsigned e = eL[i];
      int pos = atomicAdd(&cur[e & 127], 1);
      if (pos < GCAP) g[b * GCAP + pos] = (int)(e & 0xFFFFFF80u);  // src*128
    }
    if (t < 128) {
      int dst = b * 128 + t;
      int p = min(pre[t], GCAP);
      st[dst] = b * GCAP + p;
      cn[dst] = min(hist[t], GCAP - p);
    }
  }
}

// ---------- SWAR u8 accumulate ----------
__device__ __forceinline__ void accS(uint2 u, unsigned* __restrict__ a) {
  a[0] += u.x & 0x00FF00FFu;
  a[1] += __builtin_amdgcn_perm(0u, u.x, 0x04030401u);   // {0,b3,0,b1}
  a[2] += u.y & 0x00FF00FFu;
  a[3] += __builtin_amdgcn_perm(0u, u.y, 0x04030401u);
}

// single-relation group gather (authors): unroll 8; g holds src*128 byte offsets
__device__ __forceinline__ void gaccG(const unsigned char* __restrict__ base,
                                      const int* __restrict__ g, int s0, int n,
                                      int q, unsigned* __restrict__ a) {
  int i = s0;
  const int end = s0 + n;
  for (; i + 7 < end; i += 8) {
    uint2 u0 = *(const uint2*)(base + (unsigned)g[i]     + q * 8);
    uint2 u1 = *(const uint2*)(base + (unsigned)g[i + 1] + q * 8);
    uint2 u2 = *(const uint2*)(base + (unsigned)g[i + 2] + q * 8);
    uint2 u3 = *(const uint2*)(base + (unsigned)g[i + 3] + q * 8);
    uint2 u4 = *(const uint2*)(base + (unsigned)g[i + 4] + q * 8);
    uint2 u5 = *(const uint2*)(base + (unsigned)g[i + 5] + q * 8);
    uint2 u6 = *(const uint2*)(base + (unsigned)g[i + 6] + q * 8);
    uint2 u7 = *(const uint2*)(base + (unsigned)g[i + 7] + q * 8);
    accS(u0, a); accS(u1, a); accS(u2, a); accS(u3, a);
    accS(u4, a); accS(u5, a); accS(u6, a); accS(u7, a);
  }
  for (; i + 3 < end; i += 4) {
    uint2 u0 = *(const uint2*)(base + (unsigned)g[i]     + q * 8);
    uint2 u1 = *(const uint2*)(base + (unsigned)g[i + 1] + q * 8);
    uint2 u2 = *(const uint2*)(base + (unsigned)g[i + 2] + q * 8);
    uint2 u3 = *(const uint2*)(base + (unsigned)g[i + 3] + q * 8);
    accS(u0, a); accS(u1, a); accS(u2, a); accS(u3, a);
  }
  for (; i < end; i++)
    accS(*(const uint2*)(base + (unsigned)g[i] + q * 8), a);
}

// dual-relation co-issued group gather (papers)
__device__ __forceinline__ void gacc2G(const unsigned char* __restrict__ bA,
                                       const int* __restrict__ gA, int sA, int nA,
                                       const unsigned char* __restrict__ bB,
                                       const int* __restrict__ gB, int sB, int nB,
                                       int q,
                                       unsigned* __restrict__ a, unsigned* __restrict__ b) {
  int iA = sA; const int eA = sA + nA;
  int iB = sB; const int eB = sB + nB;
  bool hA = iA + 3 < eA, hB = iB + 3 < eB;
  while (hA || hB) {
    uint2 wa0, wa1, wa2, wa3, wb0, wb1, wb2, wb3;
    if (hA) {
      wa0 = *(const uint2*)(bA + (unsigned)gA[iA]     + q * 8);
      wa1 = *(const uint2*)(bA + (unsigned)gA[iA + 1] + q * 8);
      wa2 = *(const uint2*)(bA + (unsigned)gA[iA + 2] + q * 8);
      wa3 = *(const uint2*)(bA + (unsigned)gA[iA + 3] + q * 8);
    }
    if (hB) {
      wb0 = *(const uint2*)(bB + (unsigned)gB[iB]     + q * 8);
      wb1 = *(const uint2*)(bB + (unsigned)gB[iB + 1] + q * 8);
      wb2 = *(const uint2*)(bB + (unsigned)gB[iB + 2] + q * 8);
      wb3 = *(const uint2*)(bB + (unsigned)gB[iB + 3] + q * 8);
    }
    if (hA) { accS(wa0, a); accS(wa1, a); accS(wa2, a); accS(wa3, a); iA += 4; }
    if (hB) { accS(wb0, b); accS(wb1, b); accS(wb2, b); accS(wb3, b); iB += 4; }
    hA = iA + 3 < eA; hB = iB + 3 < eB;
  }
  for (; iA < eA; iA++)
    accS(*(const uint2*)(bA + (unsigned)gA[iA] + q * 8), a);
  for (; iB < eB; iB++)
    accS(*(const uint2*)(bB + (unsigned)gB[iB] + q * 8), b);
}

// unpack 4 packed accs (8 cols), bias-correct + average
__device__ __forceinline__ void unpackS(const unsigned* __restrict__ a, float nf,
                                        float invn, const float* __restrict__ bias,
                                        int q, float* __restrict__ c) {
  float s = 0.0625f * invn;
  float off = 128.0f * nf;
  float4 b0 = *(const float4*)(bias + 8 * q);
  float4 b1 = *(const float4*)(bias + 8 * q + 4);
  c[0] = ((float)(a[0] & 0xFFFFu) - off) * s + b0.x;
  c[1] = ((float)(a[1] & 0xFFFFu) - off) * s + b0.y;
  c[2] = ((float)(a[0] >> 16)     - off) * s + b0.z;
  c[3] = ((float)(a[1] >> 16)     - off) * s + b0.w;
  c[4] = ((float)(a[2] & 0xFFFFu) - off) * s + b1.x;
  c[5] = ((float)(a[3] & 0xFFFFu) - off) * s + b1.y;
  c[6] = ((float)(a[2] >> 16)     - off) * s + b1.z;
  c[7] = ((float)(a[3] >> 16)     - off) * s + b1.w;
}

// ---------- fused finalize: 4 nodes per wave (16-lane groups), 16 nodes/block ----------
__global__ __launch_bounds__(256) void k_finalize(
    const unsigned short* __restrict__ za, const unsigned short* __restrict__ zp,
    const unsigned char* __restrict__ mW8, const unsigned char* __restrict__ mB8,
    const unsigned char* __restrict__ mC8,
    const int* __restrict__ gW, const int* __restrict__ stW, const int* __restrict__ cnW,
    const int* __restrict__ gB, const int* __restrict__ stB, const int* __restrict__ cnB,
    const int* __restrict__ gC, const int* __restrict__ stC, const int* __restrict__ cnC,
    const float* __restrict__ bself_a, const float* __restrict__ bc_wb,
    const float* __restrict__ bself_p, const float* __restrict__ bc_writes,
    const float* __restrict__ bc_cites,
    const float* __restrict__ vecs, float* __restrict__ out_a, float* __restrict__ out_p,
    int NAv, int NPv, int pB) {
  const int t = threadIdx.x;
  const int lane = t & 63, q = lane & 15, grp = lane >> 4;
  const bool paper = (int)blockIdx.x < pB;
  const int node = (paper ? blockIdx.x : blockIdx.x - pB) * 16 + (t >> 6) * 4 + grp;

  if (paper) {
    if (node >= NPv) return;
    int nW = cnW[node], sW = stW[node];
    int nC = cnC[node], sC = stC[node];
    uint4 zu = *(const uint4*)((const char*)zp + (size_t)node * 256 + q * 16);
    unsigned aw[4] = {0,0,0,0}, ac[4] = {0,0,0,0};
    gacc2G(mW8, gW, sW, nW, mC8, gC, sC, nC, q, aw, ac);
    float z[8];
    z[0] = b2f((unsigned short)zu.x); z[1] = b2f((unsigned short)(zu.x >> 16));
    z[2] = b2f((unsigned short)zu.y); z[3] = b2f((unsigned short)(zu.y >> 16));
    z[4] = b2f((unsigned short)zu.z); z[5] = b2f((unsigned short)(zu.z >> 16));
    z[6] = b2f((unsigned short)zu.w); z[7] = b2f((unsigned short)(zu.w >> 16));
    float4 bs0 = *(const float4*)(bself_p + 8 * q);
    float4 bs1 = *(const float4*)(bself_p + 8 * q + 4);
    z[0] += bs0.x; z[1] += bs0.y; z[2] += bs0.z; z[3] += bs0.w;
    z[4] += bs1.x; z[5] += bs1.y; z[6] += bs1.z; z[7] += bs1.w;
    float cw[8], cc[8];
    unpackS(aw, (float)nW, frcp(fmaxf((float)nW, 1.0f)), bc_writes, q, cw);
    unpackS(ac, (float)nC, frcp(fmaxf((float)nC, 1.0f)), bc_cites, q, cc);
    float vl[8], vr[8];
    *(float4*)&vl[0] = *(const float4*)(vecs + 256 + 8 * q);
    *(float4*)&vl[4] = *(const float4*)(vecs + 256 + 8 * q + 4);
    *(float4*)&vr[0] = *(const float4*)(vecs + 384 + 8 * q);
    *(float4*)&vr[4] = *(const float4*)(vecs + 384 + 8 * q + 4);
    float srz = 0.f, slz = 0.f, slw = 0.f, slc = 0.f;
#pragma unroll
    for (int j = 0; j < 8; j++) {
      srz += z[j] * vr[j]; slz += z[j] * vl[j];
      slw += cw[j] * vl[j]; slc += cc[j] * vl[j];
    }
#pragma unroll
    for (int off = 8; off; off >>= 1) {
      srz += __shfl_xor(srz, off); slz += __shfl_xor(slz, off);
      slw += __shfl_xor(slw, off); slc += __shfl_xor(slc, off);
    }
    float cl = vecs[514], cr = vecs[515];
    float h_r = srz + cr;
    float att_s = eluf(slz + cl + h_r);
    float e_w  = eluf(slw + cl + h_r);
    float e_c  = eluf(slc + cl + h_r);
    float mx = fmaxf(att_s, fmaxf(e_w, e_c));
    float w0 = fexp(att_s - mx), w1 = fexp(e_w - mx), w2 = fexp(e_c - mx);
    float winv = frcp(w0 + w1 + w2);
    w0 *= winv; w1 *= winv; w2 *= winv;
    float o[8];
#pragma unroll
    for (int j = 0; j < 8; j++) o[j] = eluf(w0 * z[j] + w1 * cw[j] + w2 * cc[j]);
    *(float4*)(out_p + (size_t)node * 128 + 8 * q)     = *(float4*)&o[0];
    *(float4*)(out_p + (size_t)node * 128 + 8 * q + 4) = *(float4*)&o[4];
  } else {
    if (node >= NAv) return;
    int nB_ = cnB[node], sB = stB[node];
    uint4 zu = *(const uint4*)((const char*)za + (size_t)node * 256 + q * 16);
    unsigned ab[4] = {0,0,0,0};
    gaccG(mB8, gB, sB, nB_, q, ab);
    float z[8];
    z[0] = b2f((unsigned short)zu.x); z[1] = b2f((unsigned short)(zu.x >> 16));
    z[2] = b2f((unsigned short)zu.y); z[3] = b2f((unsigned short)(zu.y >> 16));
    z[4] = b2f((unsigned short)zu.z); z[5] = b2f((unsigned short)(zu.z >> 16));
    z[6] = b2f((unsigned short)zu.w); z[7] = b2f((unsigned short)(zu.w >> 16));
    float4 bs0 = *(const float4*)(bself_a + 8 * q);
    float4 bs1 = *(const float4*)(bself_a + 8 * q + 4);
    z[0] += bs0.x; z[1] += bs0.y; z[2] += bs0.z; z[3] += bs0.w;
    z[4] += bs1.x; z[5] += bs1.y; z[6] += bs1.z; z[7] += bs1.w;
    float cb[8];
    unpackS(ab, (float)nB_, frcp(fmaxf((float)nB_, 1.0f)), bc_wb, q, cb);
    float vl[8], vr[8];
    *(float4*)&vl[0] = *(const float4*)(vecs + 8 * q);
    *(float4*)&vl[4] = *(const float4*)(vecs + 8 * q + 4);
    *(float4*)&vr[0] = *(const float4*)(vecs + 128 + 8 * q);
    *(float4*)&vr[4] = *(const float4*)(vecs + 128 + 8 * q + 4);
    float srz = 0.f, slz = 0.f, slb = 0.f;
#pragma unroll
    for (int j = 0; j < 8; j++) {
      srz += z[j] * vr[j]; slz += z[j] * vl[j];
      slb += cb[j] * vl[j];
    }
#pragma unroll
    for (int off = 8; off; off >>= 1) {
      srz += __shfl_xor(srz, off); slz += __shfl_xor(slz, off);
      slb += __shfl_xor(slb, off);
    }
    float cl = vecs[512], cr = vecs[513];
    float h_r = srz + cr;
    float att_s = eluf(slz + cl + h_r);
    float e_b  = eluf(slb + cl + h_r);
    float mx = fmaxf(att_s, e_b);
    float w0 = fexp(att_s - mx), w1 = fexp(e_b - mx);
    float winv = frcp(w0 + w1);
    w0 *= winv; w1 *= winv;
    float o[8];
#pragma unroll
    for (int j = 0; j < 8; j++) o[j] = eluf(w0 * z[j] + w1 * cb[j]);
    *(float4*)(out_a + (size_t)node * 128 + 8 * q)     = *(float4*)&o[0];
    *(float4*)(out_a + (size_t)node * 128 + 8 * q + 4) = *(float4*)&o[4];
  }
}

extern "C" void kernel_launch(void* const* d_in, const int* in_sizes, int n_in,
                              void* d_out, int out_size, void* d_ws, size_t ws_size,
                              hipStream_t stream) {
  const float* h_a      = (const float*)d_in[0];
  const float* h_p      = (const float*)d_in[1];
  const float* Wself_a  = (const float*)d_in[2];  const float* bself_a = (const float*)d_in[3];
  const float* Wself_p  = (const float*)d_in[4];  const float* bself_p = (const float*)d_in[5];
  const float* Wq_a = (const float*)d_in[6];  const float* bq_a = (const float*)d_in[7];
  const float* Wq_p = (const float*)d_in[8];  const float* bq_p = (const float*)d_in[9];
  const float* Wk_a = (const float*)d_in[10]; const float* bk_a = (const float*)d_in[11];
  const float* Wk_p = (const float*)d_in[12]; const float* bk_p = (const float*)d_in[13];
  const float* Wal_a = (const float*)d_in[14]; const float* bal_a = (const float*)d_in[15];
  const float* Wal_p = (const float*)d_in[16]; const float* bal_p = (const float*)d_in[17];
  const float* War_a = (const float*)d_in[18]; const float* bar_a = (const float*)d_in[19];
  const float* War_p = (const float*)d_in[20]; const float* bar_p = (const float*)d_in[21];
  const float* Wc_writes = (const float*)d_in[22]; const float* bc_writes = (const float*)d_in[23];
  const float* Wc_wb     = (const float*)d_in[24]; const float* bc_wb     = (const float*)d_in[25];
  const float* Wc_cites  = (const float*)d_in[26]; const float* bc_cites  = (const float*)d_in[27];
  const int* w_src = (const int*)d_in[28]; const int* w_dst = (const int*)d_in[29];
  const int* b_src = (const int*)d_in[30]; const int* b_dst = (const int*)d_in[31];
  const int* c_src = (const int*)d_in[32]; const int* c_dst = (const int*)d_in[33];

  const int NA = in_sizes[0] / 256;
  const int NP = in_sizes[1] / 256;
  const int E  = in_sizes[28];
  const int ablocks = (E + CHUNK - 1) / CHUNK;   // 196

  char* ws = (char*)d_ws;
  unsigned short* BaT = (unsigned short*)(ws + 0);           // 131,072
  unsigned short* BpT = (unsigned short*)(ws + 131072);      // 196,608
  unsigned short* za  = (unsigned short*)(ws + 327680);      // MP*128*2 = 12,812,288
  unsigned short* zp  = (unsigned short*)(ws + 13139968);    // 12,812,288
  unsigned char* mW8  = (unsigned char*)(ws + 25952256);     // MP*128 = 6,406,144
  unsigned char* mB8  = (unsigned char*)(ws + 32358400);     // 6,406,144
  unsigned char* mC8  = (unsigned char*)(ws + 38764544);     // 6,406,144
  float* vecs = (float*)(ws + 45170688);                     // 2,064

  unsigned* coarse = (unsigned*)(ws + 45176832);             // 3*196*4096*4 = 9,633,792
  int*      offs   = (int*)(ws + 54810624);                  // 3*196*392*4 = 921,984
  int* gW  = (int*)(ws + 55732608);                          // NB*GCAP*4 = 4,804,608
  int* gB  = (int*)(ws + 60537216);
  int* gC  = (int*)(ws + 65341824);
  int* stW = (int*)(ws + 70146432);                          // 200,192 each
  int* stB = (int*)(ws + 70346624);
  int* stC = (int*)(ws + 70546816);
  int* cnW = (int*)(ws + 70747008);
  int* cnB = (int*)(ws + 70947200);
  int* cnC = (int*)(ws + 71147392);

  float* out_a = (float*)d_out;
  float* out_p = out_a + (size_t)NA * 128;

  k_prep<<<641 + 3 * ablocks, 256, 0, stream>>>(
      Wself_a, Wc_writes, Wself_p, Wc_wb, Wc_cites, BaT, BpT,
      Wq_a, bq_a, Wq_p, bq_p, Wk_a, bk_a, Wk_p, bk_p,
      Wal_a, bal_a, Wal_p, bal_p, War_a, bar_a, War_p, bar_p, vecs,
      w_src, w_dst, b_src, b_dst, c_src, c_dst, coarse, offs, E, ablocks);

  k_gemmA<<<GEMM_BLKS + 3 * NB, 256, 0, stream>>>(
      h_a, h_p, NA, NP, BaT, BpT, za, zp, mW8, mB8, mC8,
      coarse, offs, gW, gB, gC, stW, stB, stC, cnW, cnB, cnC, ablocks);

  int pBlk = (NP + 15) / 16, aBlk = (NA + 15) / 16;
  k_finalize<<<pBlk + aBlk, 256, 0, stream>>>(za, zp, mW8, mB8, mC8,
                                              gW, stW, cnW, gB, stB, cnB, gC, stC, cnC,
                                              bself_a, bc_wb, bself_p, bc_writes, bc_cites,
                                              vecs, out_a, out_p, NA, NP, pBlk);
}